// Round 15
// baseline (7254.418 us; speedup 1.0000x reference)
//
#include <hip/hip_runtime.h>
#include <stdint.h>

#define NPART 64
#define NBATCH 32
#define NSEQ 128
#define NEIN 64
#define NHID 256

// ---------------- JAX threefry2x32 (bit-exact) ----------------
__device__ __forceinline__ uint32_t rotl32(uint32_t x, uint32_t d) {
  return (x << d) | (x >> (32u - d));
}

__device__ __forceinline__ void threefry2x32(uint32_t k0, uint32_t k1,
                                             uint32_t& x0, uint32_t& x1) {
  uint32_t k2 = k0 ^ k1 ^ 0x1BD11BDAu;
  x0 += k0; x1 += k1;
#define TFR(r) { x0 += x1; x1 = rotl32(x1, r); x1 ^= x0; }
  TFR(13u) TFR(15u) TFR(26u) TFR(6u)
  x0 += k1; x1 += k2 + 1u;
  TFR(17u) TFR(29u) TFR(16u) TFR(24u)
  x0 += k2; x1 += k0 + 2u;
  TFR(13u) TFR(15u) TFR(26u) TFR(6u)
  x0 += k0; x1 += k1 + 3u;
  TFR(17u) TFR(29u) TFR(16u) TFR(24u)
  x0 += k1; x1 += k2 + 4u;
  TFR(13u) TFR(15u) TFR(26u) TFR(6u)
  x0 += k2; x1 += k0 + 5u;
#undef TFR
}

__device__ __forceinline__ float lreluf(float x) { return x >= 0.f ? x : 0.01f * x; }

// ---------------- prep: float4 gate-quad repack, state init, key chain -------
__global__ void k_prep(const float* __restrict__ h0, const float* __restrict__ c0,
                       const float* __restrict__ W_ih, const float* __restrict__ W_hh,
                       float* __restrict__ hA, float* __restrict__ cA,
                       float4* __restrict__ Wih4, float4* __restrict__ Whh4,
                       float* __restrict__ p_cur, float* __restrict__ y_acc,
                       int* __restrict__ idx_buf, uint2* __restrict__ subs) {
  int tid = blockIdx.x * blockDim.x + threadIdx.x;
  int nthr = gridDim.x * blockDim.x;
  for (int i = tid; i < NPART * NBATCH * NHID; i += nthr) {
    hA[i] = h0[i];
    cA[i] = c0[i];
  }
  // Wih4[e*256 + j] = (W_ih[j,e], W_ih[256+j,e], W_ih[512+j,e], W_ih[768+j,e])
  for (int i = tid; i < NEIN * NHID; i += nthr) {
    int e = i >> 8, j = i & 255;
    Wih4[i] = make_float4(W_ih[j * NEIN + e], W_ih[(256 + j) * NEIN + e],
                          W_ih[(512 + j) * NEIN + e], W_ih[(768 + j) * NEIN + e]);
  }
  // Whh4[k*256 + j] = (W_hh[j,k], W_hh[256+j,k], W_hh[512+j,k], W_hh[768+j,k])
  for (int i = tid; i < NHID * NHID; i += nthr) {
    int k = i >> 8, j = i & 255;
    Whh4[i] = make_float4(W_hh[j * NHID + k], W_hh[(256 + j) * NHID + k],
                          W_hh[(512 + j) * NHID + k], W_hh[(768 + j) * NHID + k]);
  }
  for (int i = tid; i < NPART * NBATCH; i += nthr) {
    p_cur[i] = -4.1588830833596715f;  // fp32(log(1/64))
    idx_buf[i] = i >> 5;              // identity resample for t=0 gather
  }
  for (int i = tid; i < NBATCH; i += nthr) y_acc[i] = 0.f;
  if (tid < NSEQ) {
    // threefry_partitionable split: key' = tf(key,(0,0)), sub = tf(key,(0,1))
    uint32_t k0u = 0u, k1u = 42u, sx = 0u, sy = 0u;
    for (int i = 0; i <= tid; ++i) {
      uint32_t s0 = 0u, s1 = 1u; threefry2x32(k0u, k1u, s0, s1);
      uint32_t n0 = 0u, n1 = 0u; threefry2x32(k0u, k1u, n0, n1);
      sx = s0; sy = s1; k0u = n0; k1u = n1;
    }
    subs[tid] = make_uint2(sx, sy);
  }
}

// ---------------- per-step: gates GEMM + LSTM pointwise (fp32 faithful) -------
// v9: r13 structure (XCD batch-pinning, W from L2 via plain coalesced loads --
// nt loads REVERTED, they forced W to L3/HBM latency and cost +30%) with
// 8 ROWS PER WAVE: k_step was L2-BW-bound on W re-reads (2048 waves x 256 KB
// = 512 MB/step); halving the wave count (128-thr blocks, 2 waves x 8 rows,
// grid (128,4) = 512 blocks, 2/CU) halves W L2 traffic to 256 MB/step at
// constant total FMA. Per-output math (xb loop, k ascending, one FMA per k,
// gates 0..3, epilogue) is IDENTICAL -- only the thread->output mapping
// changes -> trajectory bit-exact vs rounds 7/12/13.
__global__ __launch_bounds__(128, 2)
void k_step(int t,
            const float* __restrict__ h_prev, const float* __restrict__ c_prev,
            float* __restrict__ h_out, float* __restrict__ c_out,
            const int* __restrict__ idx_buf, const float* __restrict__ obs,
            const float4* __restrict__ Wih4, const float4* __restrict__ Whh4,
            const float* __restrict__ b_ih, const float* __restrict__ b_hh,
            float* __restrict__ y_acc, const float* __restrict__ b_out_p,
            float* __restrict__ d_out) {
  __shared__ float h_s[16][NHID];      // 16 KB
  __shared__ float obs_s[NEIN];
  __shared__ int src_s[16];
  const int tid = threadIdx.x;         // 0..127
  const int rb = blockIdx.x;   // 0..127 (fast dim -> XCD = rb%8 = b%8)
  const int cb = blockIdx.y;   // 0..3 -> h-dims [cb*64, cb*64+64)
  const int b = rb & 31;       // batch -> XCD pinned by b
  const int qg = rb >> 5;      // particle quarter (16 rows)
  const int jloc = tid & 63;
  const int rg = tid >> 6;           // wave id 0..1 -> rows rg*8 .. rg*8+7
  const int jglob = cb * 64 + jloc;  // h-dim index [0,256)

  // finalize y_out[t-1] (y_acc filled by k_pf(t-1)); reset accumulator
  if (t > 0 && cb == 0 && rb == 0 && tid < NBATCH) {
    d_out[(t - 1) * NBATCH + tid] = lreluf(y_acc[tid] + b_out_p[0]);
    y_acc[tid] = 0.f;
  }

  if (tid < NEIN) obs_s[tid] = obs[(b * NSEQ + t) * NEIN + tid];
  if (tid < 16) {
    int q = qg * 16 + tid;
    src_s[tid] = idx_buf[q * NBATCH + b] * NBATCH + b;  // resampled source row
  }
  __syncthreads();

  // gather h rows into LDS (vectorized; applies previous step's resampling).
  // L2-local: source rows were written by same-batch blocks on this XCD.
  for (int i = tid; i < 16 * (NHID / 4); i += 128) {
    int r = i >> 6, kq = i & 63;
    ((float4*)h_s[r])[kq] = ((const float4*)(h_prev + src_s[r] * NHID))[kq];
  }

  // x @ W_ih^T + b_ih + b_hh (same for all 16 rows: same batch b)
  float xb[4];
  {
    float4 w0 = make_float4(b_ih[jglob] + b_hh[jglob],
                            b_ih[jglob + 256] + b_hh[jglob + 256],
                            b_ih[jglob + 512] + b_hh[jglob + 512],
                            b_ih[jglob + 768] + b_hh[jglob + 768]);
    xb[0] = w0.x; xb[1] = w0.y; xb[2] = w0.z; xb[3] = w0.w;
  }
#pragma unroll 8
  for (int e = 0; e < NEIN; ++e) {
    float xv = obs_s[e];
    float4 w = Wih4[e * NHID + jglob];
    xb[0] += xv * w.x;
    xb[1] += xv * w.y;
    xb[2] += xv * w.z;
    xb[3] += xv * w.w;
  }

  float acc[8][4];
#pragma unroll
  for (int rr = 0; rr < 8; ++rr)
#pragma unroll
    for (int g = 0; g < 4; ++g) acc[rr][g] = 0.f;

  const float4* hrow4[8];
#pragma unroll
  for (int rr = 0; rr < 8; ++rr) hrow4[rr] = (const float4*)h_s[rg * 8 + rr];

  __syncthreads();  // h_s resident; K-loop below is barrier-free

  // W served straight from L2: one coalesced 16B load per (k, lane), now
  // amortized over 8 output rows (halved L2 W-traffic chip-wide).
  const float4* __restrict__ pW = Whh4 + cb * 64 + jloc;  // stride 256 quads/k
#pragma unroll 4
  for (int k4 = 0; k4 < 64; ++k4) {     // 4 k at a time, k ascending
    float4 h4[8], w4[4];
#pragma unroll
    for (int rr = 0; rr < 8; ++rr) h4[rr] = hrow4[rr][k4];
#pragma unroll
    for (int kk = 0; kk < 4; ++kk) w4[kk] = pW[(k4 * 4 + kk) * 256];
#pragma unroll
    for (int kk = 0; kk < 4; ++kk) {
#pragma unroll
      for (int rr = 0; rr < 8; ++rr) {
        float hv = ((const float*)&h4[rr])[kk];
        acc[rr][0] += hv * w4[kk].x;
        acc[rr][1] += hv * w4[kk].y;
        acc[rr][2] += hv * w4[kk].z;
        acc[rr][3] += hv * w4[kk].w;
      }
    }
  }

#pragma unroll
  for (int rr = 0; rr < 8; ++rr) {
    int q = qg * 16 + rg * 8 + rr;
    int n = q * NBATCH + b;
    float iv = acc[rr][0] + xb[0];
    float fv = acc[rr][1] + xb[1];
    float gv = acc[rr][2] + xb[2];
    float ov = acc[rr][3] + xb[3];
    float cp = c_prev[src_s[rg * 8 + rr] * NHID + jglob];
    float si = 1.f / (1.f + expf(-iv));
    float sf = 1.f / (1.f + expf(-fv));
    float so = 1.f / (1.f + expf(-ov));
    float c1 = sf * cp + si * tanhf(gv);
    float h1 = so * tanhf(c1);
    h_out[n * NHID + jglob] = h1;
    c_out[n * NHID + jglob] = c1;
  }
}

// ---------------- per-step: obs-loglik, softmax, resample, pf_out, y ---------
// one block per batch b; 512 threads = 8 waves. (unchanged, validated)
// blockIdx.x = b -> XCD b%8, same L2 as k_step's batch-b blocks.
__global__ __launch_bounds__(512)
void k_pf(int t, const float* __restrict__ obs, const float* __restrict__ W_obs,
          const float* __restrict__ b_obs_p, const float* __restrict__ h1,
          float* __restrict__ p_cur, int* __restrict__ idx_buf,
          const uint2* __restrict__ subs, const float* __restrict__ W_out,
          const float* __restrict__ b_out_p, float* __restrict__ y_acc,
          float* __restrict__ d_out) {
  __shared__ float logp_s[NPART], p1_s[NPART], lg_s[NPART], pdot_s[NPART];
  __shared__ int idx_s[NPART];
  __shared__ float lx_s;
  const int tid = threadIdx.x;
  const int lane = tid & 63;
  const int wv = tid >> 6;     // 0..7
  const int b = blockIdx.x;

  // ---- Phase A: obs dot (wave0) + all 64 hp dots + all 64 pdot dots ----
  float Wo[4], Wu[4];
#pragma unroll
  for (int m = 0; m < 4; ++m) {
    Wo[m] = W_obs[NEIN + m * 64 + lane];
    Wu[m] = W_out[m * 64 + lane];
  }
  if (wv == 0) {
    float v = obs[(b * NSEQ + t) * NEIN + lane] * W_obs[lane];
#pragma unroll
    for (int off = 32; off > 0; off >>= 1) v += __shfl_down(v, off, 64);
    if (lane == 0) lx_s = v + b_obs_p[0];
  }
  {
    float hv[8][4];
#pragma unroll
    for (int u = 0; u < 8; ++u) {
      const float* hr = h1 + ((wv * 8 + u) * NBATCH + b) * NHID;
#pragma unroll
      for (int m = 0; m < 4; ++m) hv[u][m] = hr[m * 64 + lane];
    }
    // logp h-part: identical FMA order (m ascending) + identical shfl tree
#pragma unroll
    for (int u = 0; u < 8; ++u) {
      float hp = 0.f;
#pragma unroll
      for (int m = 0; m < 4; ++m) hp += hv[u][m] * Wo[m];
#pragma unroll
      for (int off = 32; off > 0; off >>= 1) hp += __shfl_down(hp, off, 64);
      if (lane == 0) logp_s[wv * 8 + u] = hp;
    }
    // W_out dot per source row (gathered later through idx: bit-identical pd)
#pragma unroll
    for (int u = 0; u < 8; ++u) {
      float pd = 0.f;
#pragma unroll
      for (int m = 0; m < 4; ++m) pd += hv[u][m] * Wu[m];
#pragma unroll
      for (int off = 32; off > 0; off >>= 1) pd += __shfl_down(pd, off, 64);
      if (lane == 0) pdot_s[wv * 8 + u] = pd;
    }
  }
  __syncthreads();

  // ---- Phase B: particle softmax (wave0, math identical) ----
  if (wv == 0) {
    int n = lane * NBATCH + b;  // lane = particle q
    float x = logp_s[lane] + lx_s + p_cur[n];
    float m = x;
#pragma unroll
    for (int off = 32; off > 0; off >>= 1) {
      float o = __shfl_xor(m, off, 64);
      m = o > m ? o : m;
    }
    float s = expf(x - m);
#pragma unroll
    for (int off = 32; off > 0; off >>= 1) s += __shfl_xor(s, off, 64);
    float p1 = x - m - logf(s);
    p1_s[lane] = p1;
    lg_s[lane] = logf(0.1f * expf(p1) + 0.9f / 64.f);
  }
  __syncthreads();

  // ---- Phase C: categorical via gumbel argmax; 8 q per wave, unrolled ----
  const uint2 sub = subs[t];
  {
    float v[8]; int id[8];
#pragma unroll
    for (int u = 0; u < 8; ++u) {
      int q = wv * 8 + u;
      uint32_t x0 = 0u;
      uint32_t x1 = (uint32_t)((q * NBATCH + b) * NPART + lane);
      threefry2x32(sub.x, sub.y, x0, x1);
      uint32_t bits = x0 ^ x1;
      uint32_t mant = bits >> 9;  // uniform = mant * 2^-23 (fp32-exact)
      float uu = (mant == 0u) ? 1.17549435e-38f
                              : (float)mant * 1.1920928955078125e-07f;
      float g = -logf(-logf(uu));
      v[u] = g + lg_s[lane];
      id[u] = lane;
    }
#pragma unroll
    for (int off = 32; off > 0; off >>= 1) {
#pragma unroll
      for (int u = 0; u < 8; ++u) {
        float ov = __shfl_xor(v[u], off, 64);
        int oi = __shfl_xor(id[u], off, 64);
        if (ov > v[u] || (ov == v[u] && oi < id[u])) { v[u] = ov; id[u] = oi; }
      }
    }
    if (lane == 0) {
#pragma unroll
      for (int u = 0; u < 8; ++u) idx_s[wv * 8 + u] = id[u];
    }
  }
  __syncthreads();

  // ---- Phase D: reweight + p_cur + pf_out + y (wave0; lane = particle q) ----
  if (wv == 0) {
    int src = idx_s[lane];
    int n = lane * NBATCH + b;
    idx_buf[n] = src;
    float wn = 0.1f * expf(p1_s[src]) + 0.9f / 64.f;
    float lw = logf(wn);
    float m = lw;
#pragma unroll
    for (int off = 32; off > 0; off >>= 1) {
      float o = __shfl_xor(m, off, 64);
      m = o > m ? o : m;
    }
    float s = expf(lw - m);
#pragma unroll
    for (int off = 32; off > 0; off >>= 1) s += __shfl_xor(s, off, 64);
    float pn = lw - m - logf(s);
    p_cur[n] = pn;
    float pd = pdot_s[src];  // bit-identical to dot(h1[src*B+b], W_out)
    d_out[NSEQ * NBATCH + t * (NPART * NBATCH) + lane * NBATCH + b] =
        lreluf(pd + b_out_p[0]);
    // y = sum_q exp(p_q) * pd_q ; block b is sole owner of y_acc[b]
    float yv = expf(pn) * pd;
#pragma unroll
    for (int off = 32; off > 0; off >>= 1) yv += __shfl_down(yv, off, 64);
    if (lane == 0) y_acc[b] += yv;
  }
}

__global__ void k_final(const float* __restrict__ y_acc,
                        const float* __restrict__ b_out_p, float* __restrict__ d_out) {
  int b = threadIdx.x;
  if (b < NBATCH) {
    d_out[(NSEQ - 1) * NBATCH + b] = lreluf(y_acc[b] + b_out_p[0]);
  }
}

extern "C" void kernel_launch(void* const* d_in, const int* in_sizes, int n_in,
                              void* d_out, int out_size, void* d_ws, size_t ws_size,
                              hipStream_t stream) {
  const float* obs   = (const float*)d_in[0];
  const float* h0    = (const float*)d_in[1];
  const float* c0    = (const float*)d_in[2];
  const float* W_ih  = (const float*)d_in[3];
  const float* b_ih  = (const float*)d_in[4];
  const float* W_hh  = (const float*)d_in[5];
  const float* b_hh  = (const float*)d_in[6];
  const float* W_obs = (const float*)d_in[7];
  const float* b_obs = (const float*)d_in[8];
  const float* W_out = (const float*)d_in[9];
  const float* b_out = (const float*)d_in[10];
  float* out = (float*)d_out;

  char* w = (char*)d_ws;
  const size_t state = (size_t)NPART * NBATCH * NHID * sizeof(float);  // 2 MB
  float* hA = (float*)w;        w += state;
  float* hB = (float*)w;        w += state;
  float* cA = (float*)w;        w += state;
  float* cB = (float*)w;        w += state;
  float* p_cur = (float*)w;     w += NPART * NBATCH * sizeof(float);
  float* y_acc = (float*)w;     w += NBATCH * sizeof(float);
  uint2* subs = (uint2*)w;      w += NSEQ * sizeof(uint2);
  float4* Wih4 = (float4*)w;    w += NEIN * NHID * sizeof(float4);
  float4* Whh4 = (float4*)w;    w += NHID * NHID * sizeof(float4);
  int* idx_buf = (int*)w;       w += NPART * NBATCH * sizeof(int);

  k_prep<<<dim3(256), dim3(256), 0, stream>>>(h0, c0, W_ih, W_hh, hA, cA, Wih4, Whh4,
                                              p_cur, y_acc, idx_buf, subs);
  for (int t = 0; t < NSEQ; ++t) {
    const float* hp = (t & 1) ? hB : hA;
    float* hn       = (t & 1) ? hA : hB;
    const float* cp = (t & 1) ? cB : cA;
    float* cn       = (t & 1) ? cA : cB;
    k_step<<<dim3(128, 4), dim3(128), 0, stream>>>(
        t, hp, cp, hn, cn, idx_buf, obs, Wih4, Whh4, b_ih, b_hh, y_acc, b_out, out);
    k_pf<<<dim3(NBATCH), dim3(512), 0, stream>>>(
        t, obs, W_obs, b_obs, hn, p_cur, idx_buf, subs, W_out, b_out, y_acc, out);
  }
  k_final<<<dim3(1), dim3(64), 0, stream>>>(y_acc, b_out, out);
}

// Round 16
// 5225.748 us; speedup vs baseline: 1.3882x; 1.3882x over previous
//
#include <hip/hip_runtime.h>
#include <stdint.h>

#define NPART 64
#define NBATCH 32
#define NSEQ 128
#define NEIN 64
#define NHID 256

// ---------------- JAX threefry2x32 (bit-exact) ----------------
__device__ __forceinline__ uint32_t rotl32(uint32_t x, uint32_t d) {
  return (x << d) | (x >> (32u - d));
}

__device__ __forceinline__ void threefry2x32(uint32_t k0, uint32_t k1,
                                             uint32_t& x0, uint32_t& x1) {
  uint32_t k2 = k0 ^ k1 ^ 0x1BD11BDAu;
  x0 += k0; x1 += k1;
#define TFR(r) { x0 += x1; x1 = rotl32(x1, r); x1 ^= x0; }
  TFR(13u) TFR(15u) TFR(26u) TFR(6u)
  x0 += k1; x1 += k2 + 1u;
  TFR(17u) TFR(29u) TFR(16u) TFR(24u)
  x0 += k2; x1 += k0 + 2u;
  TFR(13u) TFR(15u) TFR(26u) TFR(6u)
  x0 += k0; x1 += k1 + 3u;
  TFR(17u) TFR(29u) TFR(16u) TFR(24u)
  x0 += k1; x1 += k2 + 4u;
  TFR(13u) TFR(15u) TFR(26u) TFR(6u)
  x0 += k2; x1 += k0 + 5u;
#undef TFR
}

__device__ __forceinline__ float lreluf(float x) { return x >= 0.f ? x : 0.01f * x; }

// ---------------- prep: float4 gate-quad repack, state init, key chain -------
__global__ void k_prep(const float* __restrict__ h0, const float* __restrict__ c0,
                       const float* __restrict__ W_ih, const float* __restrict__ W_hh,
                       float* __restrict__ hA, float* __restrict__ cA,
                       float4* __restrict__ Wih4, float4* __restrict__ Whh4,
                       float* __restrict__ p_cur, float* __restrict__ y_acc,
                       int* __restrict__ idx_buf, uint2* __restrict__ subs) {
  int tid = blockIdx.x * blockDim.x + threadIdx.x;
  int nthr = gridDim.x * blockDim.x;
  for (int i = tid; i < NPART * NBATCH * NHID; i += nthr) {
    hA[i] = h0[i];
    cA[i] = c0[i];
  }
  // Wih4[e*256 + j] = (W_ih[j,e], W_ih[256+j,e], W_ih[512+j,e], W_ih[768+j,e])
  for (int i = tid; i < NEIN * NHID; i += nthr) {
    int e = i >> 8, j = i & 255;
    Wih4[i] = make_float4(W_ih[j * NEIN + e], W_ih[(256 + j) * NEIN + e],
                          W_ih[(512 + j) * NEIN + e], W_ih[(768 + j) * NEIN + e]);
  }
  // Whh4[k*256 + j] = (W_hh[j,k], W_hh[256+j,k], W_hh[512+j,k], W_hh[768+j,k])
  for (int i = tid; i < NHID * NHID; i += nthr) {
    int k = i >> 8, j = i & 255;
    Whh4[i] = make_float4(W_hh[j * NHID + k], W_hh[(256 + j) * NHID + k],
                          W_hh[(512 + j) * NHID + k], W_hh[(768 + j) * NHID + k]);
  }
  for (int i = tid; i < NPART * NBATCH; i += nthr) {
    p_cur[i] = -4.1588830833596715f;  // fp32(log(1/64))
    idx_buf[i] = i >> 5;              // identity resample for t=0 gather
  }
  for (int i = tid; i < NBATCH; i += nthr) y_acc[i] = 0.f;
  if (tid < NSEQ) {
    // threefry_partitionable split: key' = tf(key,(0,0)), sub = tf(key,(0,1))
    uint32_t k0u = 0u, k1u = 42u, sx = 0u, sy = 0u;
    for (int i = 0; i <= tid; ++i) {
      uint32_t s0 = 0u, s1 = 1u; threefry2x32(k0u, k1u, s0, s1);
      uint32_t n0 = 0u, n1 = 0u; threefry2x32(k0u, k1u, n0, n1);
      sx = s0; sy = s1; k0u = n0; k1u = n1;
    }
    subs[tid] = make_uint2(sx, sy);
  }
}

// ---------------- per-step: gates GEMM + LSTM pointwise (fp32 faithful) -------
// v10: r13 structure (XCD batch-pinning, W from L2, h in LDS, barrier-free
// K-loop, 2 blocks/CU = 2 waves/SIMD) with a 32-row x 32-j TILE: each wave's
// two half-waves cover the SAME 32 j-quads for two 4-row sets, so the
// duplicate W addresses coalesce into one L2 request -> per-wave W traffic
// halves (256->128 KB), chip-wide 512->256 MB/step, at UNCHANGED occupancy
// (r15's 1-wave/SIMD failure mode avoided). FMA/thread, LDS reads/thread,
// per-output accumulation (xb loop, k ascending, one FMA per k, gates 0..3,
// epilogue) all identical -> trajectory bit-exact vs rounds 7/12/13.
__global__ __launch_bounds__(256, 2)
void k_step(int t,
            const float* __restrict__ h_prev, const float* __restrict__ c_prev,
            float* __restrict__ h_out, float* __restrict__ c_out,
            const int* __restrict__ idx_buf, const float* __restrict__ obs,
            const float4* __restrict__ Wih4, const float4* __restrict__ Whh4,
            const float* __restrict__ b_ih, const float* __restrict__ b_hh,
            float* __restrict__ y_acc, const float* __restrict__ b_out_p,
            float* __restrict__ d_out) {
  __shared__ float h_s[32][NHID];      // 32 KB
  __shared__ float obs_s[NEIN];
  __shared__ int src_s[32];
  const int tid = threadIdx.x;         // 0..255
  const int rb = blockIdx.x;   // 0..63 (fast dim -> XCD = rb%8 = b%8)
  const int cb = blockIdx.y;   // 0..7 -> h-dims [cb*32, cb*32+32)
  const int b = rb & 31;       // batch -> XCD pinned by b
  const int qh = rb >> 5;      // particle half: rows [qh*32, qh*32+32)
  const int jl = tid & 31;     // j-quad within slice
  const int rs = tid >> 5;     // row set 0..7 (4 rows each); wave = 2 sets
  const int jglob = cb * 32 + jl;    // h-dim index [0,256)

  // finalize y_out[t-1] (y_acc filled by k_pf(t-1)); reset accumulator
  if (t > 0 && rb == 0 && cb == 0 && tid < NBATCH) {
    d_out[(t - 1) * NBATCH + tid] = lreluf(y_acc[tid] + b_out_p[0]);
    y_acc[tid] = 0.f;
  }

  if (tid < NEIN) obs_s[tid] = obs[(b * NSEQ + t) * NEIN + tid];
  if (tid < 32) {
    int q = qh * 32 + tid;
    src_s[tid] = idx_buf[q * NBATCH + b] * NBATCH + b;  // resampled source row
  }
  __syncthreads();

  // gather h rows into LDS (vectorized; applies previous step's resampling).
  // L2-local: source rows were written by same-batch blocks on this XCD.
  for (int i = tid; i < 32 * (NHID / 4); i += 256) {
    int r = i >> 6, kq = i & 63;
    ((float4*)h_s[r])[kq] = ((const float4*)(h_prev + src_s[r] * NHID))[kq];
  }

  // x @ W_ih^T + b_ih + b_hh (same for all 32 rows: same batch b)
  float xb[4];
  {
    float4 w0 = make_float4(b_ih[jglob] + b_hh[jglob],
                            b_ih[jglob + 256] + b_hh[jglob + 256],
                            b_ih[jglob + 512] + b_hh[jglob + 512],
                            b_ih[jglob + 768] + b_hh[jglob + 768]);
    xb[0] = w0.x; xb[1] = w0.y; xb[2] = w0.z; xb[3] = w0.w;
  }
#pragma unroll 8
  for (int e = 0; e < NEIN; ++e) {
    float xv = obs_s[e];
    float4 w = Wih4[e * NHID + jglob];
    xb[0] += xv * w.x;
    xb[1] += xv * w.y;
    xb[2] += xv * w.z;
    xb[3] += xv * w.w;
  }

  float acc[4][4];
#pragma unroll
  for (int rr = 0; rr < 4; ++rr)
#pragma unroll
    for (int g = 0; g < 4; ++g) acc[rr][g] = 0.f;

  const float4* hrow4[4];
#pragma unroll
  for (int rr = 0; rr < 4; ++rr) hrow4[rr] = (const float4*)h_s[rs * 4 + rr];

  __syncthreads();  // h_s resident; K-loop below is barrier-free

  // W served straight from L2: half-wave-duplicated addresses coalesce to one
  // 512B request per load instr (half of r13's per-wave W traffic).
  const float4* __restrict__ pW = Whh4 + cb * 32 + jl;  // stride 256 quads/k
#pragma unroll 4
  for (int k4 = 0; k4 < 64; ++k4) {     // 4 k at a time, k ascending
    float4 h4[4], w4[4];
#pragma unroll
    for (int rr = 0; rr < 4; ++rr) h4[rr] = hrow4[rr][k4];
#pragma unroll
    for (int kk = 0; kk < 4; ++kk) w4[kk] = pW[(k4 * 4 + kk) * 256];
#pragma unroll
    for (int kk = 0; kk < 4; ++kk) {
#pragma unroll
      for (int rr = 0; rr < 4; ++rr) {
        float hv = ((const float*)&h4[rr])[kk];
        acc[rr][0] += hv * w4[kk].x;
        acc[rr][1] += hv * w4[kk].y;
        acc[rr][2] += hv * w4[kk].z;
        acc[rr][3] += hv * w4[kk].w;
      }
    }
  }

#pragma unroll
  for (int rr = 0; rr < 4; ++rr) {
    int q = qh * 32 + rs * 4 + rr;
    int n = q * NBATCH + b;
    float iv = acc[rr][0] + xb[0];
    float fv = acc[rr][1] + xb[1];
    float gv = acc[rr][2] + xb[2];
    float ov = acc[rr][3] + xb[3];
    float cp = c_prev[src_s[rs * 4 + rr] * NHID + jglob];
    float si = 1.f / (1.f + expf(-iv));
    float sf = 1.f / (1.f + expf(-fv));
    float so = 1.f / (1.f + expf(-ov));
    float c1 = sf * cp + si * tanhf(gv);
    float h1 = so * tanhf(c1);
    h_out[n * NHID + jglob] = h1;
    c_out[n * NHID + jglob] = c1;
  }
}

// ---------------- per-step: obs-loglik, softmax, resample, pf_out, y ---------
// one block per batch b; 512 threads = 8 waves. (unchanged, validated)
// blockIdx.x = b -> XCD b%8, same L2 as k_step's batch-b blocks.
__global__ __launch_bounds__(512)
void k_pf(int t, const float* __restrict__ obs, const float* __restrict__ W_obs,
          const float* __restrict__ b_obs_p, const float* __restrict__ h1,
          float* __restrict__ p_cur, int* __restrict__ idx_buf,
          const uint2* __restrict__ subs, const float* __restrict__ W_out,
          const float* __restrict__ b_out_p, float* __restrict__ y_acc,
          float* __restrict__ d_out) {
  __shared__ float logp_s[NPART], p1_s[NPART], lg_s[NPART], pdot_s[NPART];
  __shared__ int idx_s[NPART];
  __shared__ float lx_s;
  const int tid = threadIdx.x;
  const int lane = tid & 63;
  const int wv = tid >> 6;     // 0..7
  const int b = blockIdx.x;

  // ---- Phase A: obs dot (wave0) + all 64 hp dots + all 64 pdot dots ----
  float Wo[4], Wu[4];
#pragma unroll
  for (int m = 0; m < 4; ++m) {
    Wo[m] = W_obs[NEIN + m * 64 + lane];
    Wu[m] = W_out[m * 64 + lane];
  }
  if (wv == 0) {
    float v = obs[(b * NSEQ + t) * NEIN + lane] * W_obs[lane];
#pragma unroll
    for (int off = 32; off > 0; off >>= 1) v += __shfl_down(v, off, 64);
    if (lane == 0) lx_s = v + b_obs_p[0];
  }
  {
    float hv[8][4];
#pragma unroll
    for (int u = 0; u < 8; ++u) {
      const float* hr = h1 + ((wv * 8 + u) * NBATCH + b) * NHID;
#pragma unroll
      for (int m = 0; m < 4; ++m) hv[u][m] = hr[m * 64 + lane];
    }
    // logp h-part: identical FMA order (m ascending) + identical shfl tree
#pragma unroll
    for (int u = 0; u < 8; ++u) {
      float hp = 0.f;
#pragma unroll
      for (int m = 0; m < 4; ++m) hp += hv[u][m] * Wo[m];
#pragma unroll
      for (int off = 32; off > 0; off >>= 1) hp += __shfl_down(hp, off, 64);
      if (lane == 0) logp_s[wv * 8 + u] = hp;
    }
    // W_out dot per source row (gathered later through idx: bit-identical pd)
#pragma unroll
    for (int u = 0; u < 8; ++u) {
      float pd = 0.f;
#pragma unroll
      for (int m = 0; m < 4; ++m) pd += hv[u][m] * Wu[m];
#pragma unroll
      for (int off = 32; off > 0; off >>= 1) pd += __shfl_down(pd, off, 64);
      if (lane == 0) pdot_s[wv * 8 + u] = pd;
    }
  }
  __syncthreads();

  // ---- Phase B: particle softmax (wave0, math identical) ----
  if (wv == 0) {
    int n = lane * NBATCH + b;  // lane = particle q
    float x = logp_s[lane] + lx_s + p_cur[n];
    float m = x;
#pragma unroll
    for (int off = 32; off > 0; off >>= 1) {
      float o = __shfl_xor(m, off, 64);
      m = o > m ? o : m;
    }
    float s = expf(x - m);
#pragma unroll
    for (int off = 32; off > 0; off >>= 1) s += __shfl_xor(s, off, 64);
    float p1 = x - m - logf(s);
    p1_s[lane] = p1;
    lg_s[lane] = logf(0.1f * expf(p1) + 0.9f / 64.f);
  }
  __syncthreads();

  // ---- Phase C: categorical via gumbel argmax; 8 q per wave, unrolled ----
  const uint2 sub = subs[t];
  {
    float v[8]; int id[8];
#pragma unroll
    for (int u = 0; u < 8; ++u) {
      int q = wv * 8 + u;
      uint32_t x0 = 0u;
      uint32_t x1 = (uint32_t)((q * NBATCH + b) * NPART + lane);
      threefry2x32(sub.x, sub.y, x0, x1);
      uint32_t bits = x0 ^ x1;
      uint32_t mant = bits >> 9;  // uniform = mant * 2^-23 (fp32-exact)
      float uu = (mant == 0u) ? 1.17549435e-38f
                              : (float)mant * 1.1920928955078125e-07f;
      float g = -logf(-logf(uu));
      v[u] = g + lg_s[lane];
      id[u] = lane;
    }
#pragma unroll
    for (int off = 32; off > 0; off >>= 1) {
#pragma unroll
      for (int u = 0; u < 8; ++u) {
        float ov = __shfl_xor(v[u], off, 64);
        int oi = __shfl_xor(id[u], off, 64);
        if (ov > v[u] || (ov == v[u] && oi < id[u])) { v[u] = ov; id[u] = oi; }
      }
    }
    if (lane == 0) {
#pragma unroll
      for (int u = 0; u < 8; ++u) idx_s[wv * 8 + u] = id[u];
    }
  }
  __syncthreads();

  // ---- Phase D: reweight + p_cur + pf_out + y (wave0; lane = particle q) ----
  if (wv == 0) {
    int src = idx_s[lane];
    int n = lane * NBATCH + b;
    idx_buf[n] = src;
    float wn = 0.1f * expf(p1_s[src]) + 0.9f / 64.f;
    float lw = logf(wn);
    float m = lw;
#pragma unroll
    for (int off = 32; off > 0; off >>= 1) {
      float o = __shfl_xor(m, off, 64);
      m = o > m ? o : m;
    }
    float s = expf(lw - m);
#pragma unroll
    for (int off = 32; off > 0; off >>= 1) s += __shfl_xor(s, off, 64);
    float pn = lw - m - logf(s);
    p_cur[n] = pn;
    float pd = pdot_s[src];  // bit-identical to dot(h1[src*B+b], W_out)
    d_out[NSEQ * NBATCH + t * (NPART * NBATCH) + lane * NBATCH + b] =
        lreluf(pd + b_out_p[0]);
    // y = sum_q exp(p_q) * pd_q ; block b is sole owner of y_acc[b]
    float yv = expf(pn) * pd;
#pragma unroll
    for (int off = 32; off > 0; off >>= 1) yv += __shfl_down(yv, off, 64);
    if (lane == 0) y_acc[b] += yv;
  }
}

__global__ void k_final(const float* __restrict__ y_acc,
                        const float* __restrict__ b_out_p, float* __restrict__ d_out) {
  int b = threadIdx.x;
  if (b < NBATCH) {
    d_out[(NSEQ - 1) * NBATCH + b] = lreluf(y_acc[b] + b_out_p[0]);
  }
}

extern "C" void kernel_launch(void* const* d_in, const int* in_sizes, int n_in,
                              void* d_out, int out_size, void* d_ws, size_t ws_size,
                              hipStream_t stream) {
  const float* obs   = (const float*)d_in[0];
  const float* h0    = (const float*)d_in[1];
  const float* c0    = (const float*)d_in[2];
  const float* W_ih  = (const float*)d_in[3];
  const float* b_ih  = (const float*)d_in[4];
  const float* W_hh  = (const float*)d_in[5];
  const float* b_hh  = (const float*)d_in[6];
  const float* W_obs = (const float*)d_in[7];
  const float* b_obs = (const float*)d_in[8];
  const float* W_out = (const float*)d_in[9];
  const float* b_out = (const float*)d_in[10];
  float* out = (float*)d_out;

  char* w = (char*)d_ws;
  const size_t state = (size_t)NPART * NBATCH * NHID * sizeof(float);  // 2 MB
  float* hA = (float*)w;        w += state;
  float* hB = (float*)w;        w += state;
  float* cA = (float*)w;        w += state;
  float* cB = (float*)w;        w += state;
  float* p_cur = (float*)w;     w += NPART * NBATCH * sizeof(float);
  float* y_acc = (float*)w;     w += NBATCH * sizeof(float);
  uint2* subs = (uint2*)w;      w += NSEQ * sizeof(uint2);
  float4* Wih4 = (float4*)w;    w += NEIN * NHID * sizeof(float4);
  float4* Whh4 = (float4*)w;    w += NHID * NHID * sizeof(float4);
  int* idx_buf = (int*)w;       w += NPART * NBATCH * sizeof(int);

  k_prep<<<dim3(256), dim3(256), 0, stream>>>(h0, c0, W_ih, W_hh, hA, cA, Wih4, Whh4,
                                              p_cur, y_acc, idx_buf, subs);
  for (int t = 0; t < NSEQ; ++t) {
    const float* hp = (t & 1) ? hB : hA;
    float* hn       = (t & 1) ? hA : hB;
    const float* cp = (t & 1) ? cB : cA;
    float* cn       = (t & 1) ? cA : cB;
    k_step<<<dim3(64, 8), dim3(256), 0, stream>>>(
        t, hp, cp, hn, cn, idx_buf, obs, Wih4, Whh4, b_ih, b_hh, y_acc, b_out, out);
    k_pf<<<dim3(NBATCH), dim3(512), 0, stream>>>(
        t, obs, W_obs, b_obs, hn, p_cur, idx_buf, subs, W_out, b_out, y_acc, out);
  }
  k_final<<<dim3(1), dim3(64), 0, stream>>>(y_acc, b_out, out);
}

// Round 19
// 5209.000 us; speedup vs baseline: 1.3927x; 1.0032x over previous
//
#include <hip/hip_runtime.h>
#include <stdint.h>

#define NPART 64
#define NBATCH 32
#define NSEQ 128
#define NEIN 64
#define NHID 256

// ---------------- JAX threefry2x32 (bit-exact) ----------------
__device__ __forceinline__ uint32_t rotl32(uint32_t x, uint32_t d) {
  return (x << d) | (x >> (32u - d));
}

__device__ __forceinline__ void threefry2x32(uint32_t k0, uint32_t k1,
                                             uint32_t& x0, uint32_t& x1) {
  uint32_t k2 = k0 ^ k1 ^ 0x1BD11BDAu;
  x0 += k0; x1 += k1;
#define TFR(r) { x0 += x1; x1 = rotl32(x1, r); x1 ^= x0; }
  TFR(13u) TFR(15u) TFR(26u) TFR(6u)
  x0 += k1; x1 += k2 + 1u;
  TFR(17u) TFR(29u) TFR(16u) TFR(24u)
  x0 += k2; x1 += k0 + 2u;
  TFR(13u) TFR(15u) TFR(26u) TFR(6u)
  x0 += k0; x1 += k1 + 3u;
  TFR(17u) TFR(29u) TFR(16u) TFR(24u)
  x0 += k1; x1 += k2 + 4u;
  TFR(13u) TFR(15u) TFR(26u) TFR(6u)
  x0 += k2; x1 += k0 + 5u;
#undef TFR
}

__device__ __forceinline__ float lreluf(float x) { return x >= 0.f ? x : 0.01f * x; }

// ---------------- prep: float4 gate-quad repack, state init, key chain -------
__global__ void k_prep(const float* __restrict__ h0, const float* __restrict__ c0,
                       const float* __restrict__ W_ih, const float* __restrict__ W_hh,
                       float* __restrict__ hA, float* __restrict__ cA,
                       float4* __restrict__ Wih4, float4* __restrict__ Whh4,
                       float* __restrict__ p_cur, float* __restrict__ y_acc,
                       int* __restrict__ idx_buf, uint2* __restrict__ subs) {
  int tid = blockIdx.x * blockDim.x + threadIdx.x;
  int nthr = gridDim.x * blockDim.x;
  for (int i = tid; i < NPART * NBATCH * NHID; i += nthr) {
    hA[i] = h0[i];
    cA[i] = c0[i];
  }
  // Wih4[e*256 + j] = (W_ih[j,e], W_ih[256+j,e], W_ih[512+j,e], W_ih[768+j,e])
  for (int i = tid; i < NEIN * NHID; i += nthr) {
    int e = i >> 8, j = i & 255;
    Wih4[i] = make_float4(W_ih[j * NEIN + e], W_ih[(256 + j) * NEIN + e],
                          W_ih[(512 + j) * NEIN + e], W_ih[(768 + j) * NEIN + e]);
  }
  // Whh4[k*256 + j] = (W_hh[j,k], W_hh[256+j,k], W_hh[512+j,k], W_hh[768+j,k])
  for (int i = tid; i < NHID * NHID; i += nthr) {
    int k = i >> 8, j = i & 255;
    Whh4[i] = make_float4(W_hh[j * NHID + k], W_hh[(256 + j) * NHID + k],
                          W_hh[(512 + j) * NHID + k], W_hh[(768 + j) * NHID + k]);
  }
  for (int i = tid; i < NPART * NBATCH; i += nthr) {
    p_cur[i] = -4.1588830833596715f;  // fp32(log(1/64))
    idx_buf[i] = i >> 5;              // identity resample for t=0 gather
  }
  for (int i = tid; i < NBATCH; i += nthr) y_acc[i] = 0.f;
  if (tid < NSEQ) {
    // threefry_partitionable split: key' = tf(key,(0,0)), sub = tf(key,(0,1))
    uint32_t k0u = 0u, k1u = 42u, sx = 0u, sy = 0u;
    for (int i = 0; i <= tid; ++i) {
      uint32_t s0 = 0u, s1 = 1u; threefry2x32(k0u, k1u, s0, s1);
      uint32_t n0 = 0u, n1 = 0u; threefry2x32(k0u, k1u, n0, n1);
      sx = s0; sy = s1; k0u = n0; k1u = n1;
    }
    subs[tid] = make_uint2(sx, sy);
  }
}

// ---------------- per-step: gates GEMM + LSTM pointwise (fp32 faithful) -------
// v10 (final): XCD batch-pinning (grid rb-fast, b = rb&31 -> all 16 blocks of
// batch b AND k_pf's block b on XCD b%8; batch state L2-resident across all
// 128 steps) + 32-row x 32-j tile: each wave's two half-waves cover the SAME
// 32 j-quads for two 4-row sets, so duplicate W addresses coalesce into one
// L2 request -> per-wave W traffic halves vs r13 at unchanged occupancy
// (2 blocks/CU = 2 waves/SIMD). W served from L2 by plain coalesced loads
// (no LDS staging; LDS carries only the h broadcasts). Zero barriers in the
// K-loop. Per-output accumulation (xb loop, k ascending, one FMA per k,
// gates 0..3, epilogue) == the validated round-7/12/13 math -> bit-exact.
__global__ __launch_bounds__(256, 2)
void k_step(int t,
            const float* __restrict__ h_prev, const float* __restrict__ c_prev,
            float* __restrict__ h_out, float* __restrict__ c_out,
            const int* __restrict__ idx_buf, const float* __restrict__ obs,
            const float4* __restrict__ Wih4, const float4* __restrict__ Whh4,
            const float* __restrict__ b_ih, const float* __restrict__ b_hh,
            float* __restrict__ y_acc, const float* __restrict__ b_out_p,
            float* __restrict__ d_out) {
  __shared__ float h_s[32][NHID];      // 32 KB
  __shared__ float obs_s[NEIN];
  __shared__ int src_s[32];
  const int tid = threadIdx.x;         // 0..255
  const int rb = blockIdx.x;   // 0..63 (fast dim -> XCD = rb%8 = b%8)
  const int cb = blockIdx.y;   // 0..7 -> h-dims [cb*32, cb*32+32)
  const int b = rb & 31;       // batch -> XCD pinned by b
  const int qh = rb >> 5;      // particle half: rows [qh*32, qh*32+32)
  const int jl = tid & 31;     // j-quad within slice
  const int rs = tid >> 5;     // row set 0..7 (4 rows each); wave = 2 sets
  const int jglob = cb * 32 + jl;    // h-dim index [0,256)

  // finalize y_out[t-1] (y_acc filled by k_pf(t-1)); reset accumulator
  if (t > 0 && rb == 0 && cb == 0 && tid < NBATCH) {
    d_out[(t - 1) * NBATCH + tid] = lreluf(y_acc[tid] + b_out_p[0]);
    y_acc[tid] = 0.f;
  }

  if (tid < NEIN) obs_s[tid] = obs[(b * NSEQ + t) * NEIN + tid];
  if (tid < 32) {
    int q = qh * 32 + tid;
    src_s[tid] = idx_buf[q * NBATCH + b] * NBATCH + b;  // resampled source row
  }
  __syncthreads();

  // gather h rows into LDS (vectorized; applies previous step's resampling).
  // L2-local: source rows were written by same-batch blocks on this XCD.
  for (int i = tid; i < 32 * (NHID / 4); i += 256) {
    int r = i >> 6, kq = i & 63;
    ((float4*)h_s[r])[kq] = ((const float4*)(h_prev + src_s[r] * NHID))[kq];
  }

  // x @ W_ih^T + b_ih + b_hh (same for all 32 rows: same batch b)
  float xb[4];
  {
    float4 w0 = make_float4(b_ih[jglob] + b_hh[jglob],
                            b_ih[jglob + 256] + b_hh[jglob + 256],
                            b_ih[jglob + 512] + b_hh[jglob + 512],
                            b_ih[jglob + 768] + b_hh[jglob + 768]);
    xb[0] = w0.x; xb[1] = w0.y; xb[2] = w0.z; xb[3] = w0.w;
  }
#pragma unroll 8
  for (int e = 0; e < NEIN; ++e) {
    float xv = obs_s[e];
    float4 w = Wih4[e * NHID + jglob];
    xb[0] += xv * w.x;
    xb[1] += xv * w.y;
    xb[2] += xv * w.z;
    xb[3] += xv * w.w;
  }

  float acc[4][4];
#pragma unroll
  for (int rr = 0; rr < 4; ++rr)
#pragma unroll
    for (int g = 0; g < 4; ++g) acc[rr][g] = 0.f;

  const float4* hrow4[4];
#pragma unroll
  for (int rr = 0; rr < 4; ++rr) hrow4[rr] = (const float4*)h_s[rs * 4 + rr];

  __syncthreads();  // h_s resident; K-loop below is barrier-free

  // W served straight from L2: half-wave-duplicated addresses coalesce to one
  // 512B request per load instr (half of r13's per-wave W traffic).
  const float4* __restrict__ pW = Whh4 + cb * 32 + jl;  // stride 256 quads/k
#pragma unroll 4
  for (int k4 = 0; k4 < 64; ++k4) {     // 4 k at a time, k ascending
    float4 h4[4], w4[4];
#pragma unroll
    for (int rr = 0; rr < 4; ++rr) h4[rr] = hrow4[rr][k4];
#pragma unroll
    for (int kk = 0; kk < 4; ++kk) w4[kk] = pW[(k4 * 4 + kk) * 256];
#pragma unroll
    for (int kk = 0; kk < 4; ++kk) {
#pragma unroll
      for (int rr = 0; rr < 4; ++rr) {
        float hv = ((const float*)&h4[rr])[kk];
        acc[rr][0] += hv * w4[kk].x;
        acc[rr][1] += hv * w4[kk].y;
        acc[rr][2] += hv * w4[kk].z;
        acc[rr][3] += hv * w4[kk].w;
      }
    }
  }

#pragma unroll
  for (int rr = 0; rr < 4; ++rr) {
    int q = qh * 32 + rs * 4 + rr;
    int n = q * NBATCH + b;
    float iv = acc[rr][0] + xb[0];
    float fv = acc[rr][1] + xb[1];
    float gv = acc[rr][2] + xb[2];
    float ov = acc[rr][3] + xb[3];
    float cp = c_prev[src_s[rs * 4 + rr] * NHID + jglob];
    float si = 1.f / (1.f + expf(-iv));
    float sf = 1.f / (1.f + expf(-fv));
    float so = 1.f / (1.f + expf(-ov));
    float c1 = sf * cp + si * tanhf(gv);
    float h1 = so * tanhf(c1);
    h_out[n * NHID + jglob] = h1;
    c_out[n * NHID + jglob] = c1;
  }
}

// ---------------- per-step: obs-loglik, softmax, resample, pf_out, y ---------
// one block per batch b; 512 threads = 8 waves. (unchanged, validated)
// blockIdx.x = b -> XCD b%8, same L2 as k_step's batch-b blocks.
__global__ __launch_bounds__(512)
void k_pf(int t, const float* __restrict__ obs, const float* __restrict__ W_obs,
          const float* __restrict__ b_obs_p, const float* __restrict__ h1,
          float* __restrict__ p_cur, int* __restrict__ idx_buf,
          const uint2* __restrict__ subs, const float* __restrict__ W_out,
          const float* __restrict__ b_out_p, float* __restrict__ y_acc,
          float* __restrict__ d_out) {
  __shared__ float logp_s[NPART], p1_s[NPART], lg_s[NPART], pdot_s[NPART];
  __shared__ int idx_s[NPART];
  __shared__ float lx_s;
  const int tid = threadIdx.x;
  const int lane = tid & 63;
  const int wv = tid >> 6;     // 0..7
  const int b = blockIdx.x;

  // ---- Phase A: obs dot (wave0) + all 64 hp dots + all 64 pdot dots ----
  float Wo[4], Wu[4];
#pragma unroll
  for (int m = 0; m < 4; ++m) {
    Wo[m] = W_obs[NEIN + m * 64 + lane];
    Wu[m] = W_out[m * 64 + lane];
  }
  if (wv == 0) {
    float v = obs[(b * NSEQ + t) * NEIN + lane] * W_obs[lane];
#pragma unroll
    for (int off = 32; off > 0; off >>= 1) v += __shfl_down(v, off, 64);
    if (lane == 0) lx_s = v + b_obs_p[0];
  }
  {
    float hv[8][4];
#pragma unroll
    for (int u = 0; u < 8; ++u) {
      const float* hr = h1 + ((wv * 8 + u) * NBATCH + b) * NHID;
#pragma unroll
      for (int m = 0; m < 4; ++m) hv[u][m] = hr[m * 64 + lane];
    }
    // logp h-part: identical FMA order (m ascending) + identical shfl tree
#pragma unroll
    for (int u = 0; u < 8; ++u) {
      float hp = 0.f;
#pragma unroll
      for (int m = 0; m < 4; ++m) hp += hv[u][m] * Wo[m];
#pragma unroll
      for (int off = 32; off > 0; off >>= 1) hp += __shfl_down(hp, off, 64);
      if (lane == 0) logp_s[wv * 8 + u] = hp;
    }
    // W_out dot per source row (gathered later through idx: bit-identical pd)
#pragma unroll
    for (int u = 0; u < 8; ++u) {
      float pd = 0.f;
#pragma unroll
      for (int m = 0; m < 4; ++m) pd += hv[u][m] * Wu[m];
#pragma unroll
      for (int off = 32; off > 0; off >>= 1) pd += __shfl_down(pd, off, 64);
      if (lane == 0) pdot_s[wv * 8 + u] = pd;
    }
  }
  __syncthreads();

  // ---- Phase B: particle softmax (wave0, math identical) ----
  if (wv == 0) {
    int n = lane * NBATCH + b;  // lane = particle q
    float x = logp_s[lane] + lx_s + p_cur[n];
    float m = x;
#pragma unroll
    for (int off = 32; off > 0; off >>= 1) {
      float o = __shfl_xor(m, off, 64);
      m = o > m ? o : m;
    }
    float s = expf(x - m);
#pragma unroll
    for (int off = 32; off > 0; off >>= 1) s += __shfl_xor(s, off, 64);
    float p1 = x - m - logf(s);
    p1_s[lane] = p1;
    lg_s[lane] = logf(0.1f * expf(p1) + 0.9f / 64.f);
  }
  __syncthreads();

  // ---- Phase C: categorical via gumbel argmax; 8 q per wave, unrolled ----
  const uint2 sub = subs[t];
  {
    float v[8]; int id[8];
#pragma unroll
    for (int u = 0; u < 8; ++u) {
      int q = wv * 8 + u;
      uint32_t x0 = 0u;
      uint32_t x1 = (uint32_t)((q * NBATCH + b) * NPART + lane);
      threefry2x32(sub.x, sub.y, x0, x1);
      uint32_t bits = x0 ^ x1;
      uint32_t mant = bits >> 9;  // uniform = mant * 2^-23 (fp32-exact)
      float uu = (mant == 0u) ? 1.17549435e-38f
                              : (float)mant * 1.1920928955078125e-07f;
      float g = -logf(-logf(uu));
      v[u] = g + lg_s[lane];
      id[u] = lane;
    }
#pragma unroll
    for (int off = 32; off > 0; off >>= 1) {
#pragma unroll
      for (int u = 0; u < 8; ++u) {
        float ov = __shfl_xor(v[u], off, 64);
        int oi = __shfl_xor(id[u], off, 64);
        if (ov > v[u] || (ov == v[u] && oi < id[u])) { v[u] = ov; id[u] = oi; }
      }
    }
    if (lane == 0) {
#pragma unroll
      for (int u = 0; u < 8; ++u) idx_s[wv * 8 + u] = id[u];
    }
  }
  __syncthreads();

  // ---- Phase D: reweight + p_cur + pf_out + y (wave0; lane = particle q) ----
  if (wv == 0) {
    int src = idx_s[lane];
    int n = lane * NBATCH + b;
    idx_buf[n] = src;
    float wn = 0.1f * expf(p1_s[src]) + 0.9f / 64.f;
    float lw = logf(wn);
    float m = lw;
#pragma unroll
    for (int off = 32; off > 0; off >>= 1) {
      float o = __shfl_xor(m, off, 64);
      m = o > m ? o : m;
    }
    float s = expf(lw - m);
#pragma unroll
    for (int off = 32; off > 0; off >>= 1) s += __shfl_xor(s, off, 64);
    float pn = lw - m - logf(s);
    p_cur[n] = pn;
    float pd = pdot_s[src];  // bit-identical to dot(h1[src*B+b], W_out)
    d_out[NSEQ * NBATCH + t * (NPART * NBATCH) + lane * NBATCH + b] =
        lreluf(pd + b_out_p[0]);
    // y = sum_q exp(p_q) * pd_q ; block b is sole owner of y_acc[b]
    float yv = expf(pn) * pd;
#pragma unroll
    for (int off = 32; off > 0; off >>= 1) yv += __shfl_down(yv, off, 64);
    if (lane == 0) y_acc[b] += yv;
  }
}

__global__ void k_final(const float* __restrict__ y_acc,
                        const float* __restrict__ b_out_p, float* __restrict__ d_out) {
  int b = threadIdx.x;
  if (b < NBATCH) {
    d_out[(NSEQ - 1) * NBATCH + b] = lreluf(y_acc[b] + b_out_p[0]);
  }
}

extern "C" void kernel_launch(void* const* d_in, const int* in_sizes, int n_in,
                              void* d_out, int out_size, void* d_ws, size_t ws_size,
                              hipStream_t stream) {
  const float* obs   = (const float*)d_in[0];
  const float* h0    = (const float*)d_in[1];
  const float* c0    = (const float*)d_in[2];
  const float* W_ih  = (const float*)d_in[3];
  const float* b_ih  = (const float*)d_in[4];
  const float* W_hh  = (const float*)d_in[5];
  const float* b_hh  = (const float*)d_in[6];
  const float* W_obs = (const float*)d_in[7];
  const float* b_obs = (const float*)d_in[8];
  const float* W_out = (const float*)d_in[9];
  const float* b_out = (const float*)d_in[10];
  float* out = (float*)d_out;

  char* w = (char*)d_ws;
  const size_t state = (size_t)NPART * NBATCH * NHID * sizeof(float);  // 2 MB
  float* hA = (float*)w;        w += state;
  float* hB = (float*)w;        w += state;
  float* cA = (float*)w;        w += state;
  float* cB = (float*)w;        w += state;
  float* p_cur = (float*)w;     w += NPART * NBATCH * sizeof(float);
  float* y_acc = (float*)w;     w += NBATCH * sizeof(float);
  uint2* subs = (uint2*)w;      w += NSEQ * sizeof(uint2);
  float4* Wih4 = (float4*)w;    w += NEIN * NHID * sizeof(float4);
  float4* Whh4 = (float4*)w;    w += NHID * NHID * sizeof(float4);
  int* idx_buf = (int*)w;       w += NPART * NBATCH * sizeof(int);

  k_prep<<<dim3(256), dim3(256), 0, stream>>>(h0, c0, W_ih, W_hh, hA, cA, Wih4, Whh4,
                                              p_cur, y_acc, idx_buf, subs);
  for (int t = 0; t < NSEQ; ++t) {
    const float* hp = (t & 1) ? hB : hA;
    float* hn       = (t & 1) ? hA : hB;
    const float* cp = (t & 1) ? cB : cA;
    float* cn       = (t & 1) ? cA : cB;
    k_step<<<dim3(64, 8), dim3(256), 0, stream>>>(
        t, hp, cp, hn, cn, idx_buf, obs, Wih4, Whh4, b_ih, b_hh, y_acc, b_out, out);
    k_pf<<<dim3(NBATCH), dim3(512), 0, stream>>>(
        t, obs, W_obs, b_obs, hn, p_cur, idx_buf, subs, W_out, b_out, y_acc, out);
  }
  k_final<<<dim3(1), dim3(64), 0, stream>>>(y_acc, b_out, out);
}